// Round 8
// baseline (116.887 us; speedup 1.0000x reference)
//
#include <hip/hip_runtime.h>
#include <math.h>

#define NTOT   12
#define DIM    4096      // 2^12
#define LAYERS 4
#define NB     1024      // batch
// phys(i) = i + (i>>6): Q slots (amp l*64+j) -> 65l + j (contiguous per thread),
// P slots (amp j*64+l) -> 65j + l (consecutive per lane). Both: 4 lanes/bank-pair.
#define SPAD   4160

typedef float v2f __attribute__((ext_vector_type(2)));

// Fused (Ry*Rx) SU(2) gate on local bit G of a 64-amp register block, complex
// interleaved (lo=re, hi=im). Coefficients packed: P1=(cc,cs), P2=(ss,sc).
// 8 v_pk_*_f32 per pair; swaps/negs via op_sel / neg modifiers.
template<int G>
__device__ __forceinline__ void gate_pk64(v2f (&x)[64], v2f P1, v2f P2) {
#pragma unroll
    for (int p = 0; p < 32; ++p) {
        const int j0 = ((p >> G) << (G + 1)) | (p & ((1 << G) - 1));
        const int j1 = j0 | (1 << G);
        const v2f x0 = x[j0], x1 = x[j1];
        v2f t, u;
        asm("v_pk_mul_f32 %0, %1, %2 op_sel:[1,1] op_sel_hi:[1,0] neg_hi:[1,0]"
            : "=v"(t) : "v"(P2), "v"(x1));
        asm("v_pk_fma_f32 %0, %1, %2, %0 op_sel:[1,0,0] op_sel_hi:[1,1,1] neg_lo:[1,0,0] neg_hi:[1,0,0]"
            : "+v"(t) : "v"(P1), "v"(x1));
        asm("v_pk_fma_f32 %0, %1, %2, %0 op_sel:[0,1,0] op_sel_hi:[0,0,1] neg_lo:[1,0,0]"
            : "+v"(t) : "v"(P2), "v"(x0));
        asm("v_pk_fma_f32 %0, %1, %2, %0 op_sel:[0,0,0] op_sel_hi:[0,1,1]"
            : "+v"(t) : "v"(P1), "v"(x0));
        asm("v_pk_mul_f32 %0, %1, %2 op_sel:[0,1] op_sel_hi:[0,0] neg_hi:[1,0]"
            : "=v"(u) : "v"(P2), "v"(x1));
        asm("v_pk_fma_f32 %0, %1, %2, %0 op_sel:[0,0,0] op_sel_hi:[0,1,1]"
            : "+v"(u) : "v"(P1), "v"(x1));
        asm("v_pk_fma_f32 %0, %1, %2, %0 op_sel:[1,1,0] op_sel_hi:[1,0,1] neg_hi:[1,0,0]"
            : "+v"(u) : "v"(P2), "v"(x0));
        asm("v_pk_fma_f32 %0, %1, %2, %0 op_sel:[1,0,0] op_sel_hi:[1,1,1]"
            : "+v"(u) : "v"(P1), "v"(x0));
        x[j0] = t; x[j1] = u;
    }
}

// Apply the 6 gates of one partition of one layer.
// Local reg bit G corresponds to gate index (top - G): for the P partition
// (amp bits 11:6 in regs) top = lay*12+5 (bit g -> qubit 5-g); for the Q
// partition (amp bits 5:0) top = lay*12+11 (bit g -> qubit 11-g).
__device__ __forceinline__ void apply6(v2f (&x)[64], const float4* gco, int top) {
    float4 c;
    c = gco[top - 0]; gate_pk64<0>(x, (v2f){c.x, c.y}, (v2f){c.z, c.w});
    c = gco[top - 1]; gate_pk64<1>(x, (v2f){c.x, c.y}, (v2f){c.z, c.w});
    c = gco[top - 2]; gate_pk64<2>(x, (v2f){c.x, c.y}, (v2f){c.z, c.w});
    c = gco[top - 3]; gate_pk64<3>(x, (v2f){c.x, c.y}, (v2f){c.z, c.w});
    c = gco[top - 4]; gate_pk64<4>(x, (v2f){c.x, c.y}, (v2f){c.z, c.w});
    c = gco[top - 5]; gate_pk64<5>(x, (v2f){c.x, c.y}, (v2f){c.z, c.w});
}

// CZ diagonal via per-thread 64-bit sign mask (bit j -> amp j of this block).
__device__ __forceinline__ void applyCZ64(v2f (&x)[64], unsigned long long mask) {
#pragma unroll
    for (int j = 0; j < 64; ++j) {
        const unsigned int w = (j < 32) ? (unsigned int)mask : (unsigned int)(mask >> 32);
        const unsigned int sw = (w << (31 - (j & 31))) & 0x80000000u;
        x[j].x = __uint_as_float(__float_as_uint(x[j].x) ^ sw);
        x[j].y = __uint_as_float(__float_as_uint(x[j].y) ^ sw);
    }
}

// bit v of KPAR = parity(popc(v & (v>>1) & 0x1F)) for 6-bit v: the CZ-sign
// parity of adjacent-bit products within a 6-bit field.
#define KPAR 0xB8B7B8484748B848ULL

// One wave (64 threads) per sample; thread l holds 64 amps in registers.
//   Q partition: amps l*64 + j  (reg bit g = amp bit g = qubit 11-g)
//   P partition: amps j*64 + l  (reg bit g = amp bit 6+g = qubit 5-g)
// Schedule per layer: P(q0..5) | Q(q6..11) + CZ. 8 LDS passes, ZERO
// __syncthreads (all exchanges same-wave via the in-order DS pipe).
// Occupancy is intentionally 4 waves/CU (LDS-capped): one wave saturates its
// SIMD's FP32 pipe (1 pk-op / 4 cyc, 32 independent pairs per gate).
__global__ __launch_bounds__(64, 1) void qddpm_kernel(
    const float* __restrict__ in_re,
    const float* __restrict__ in_im,
    const float* __restrict__ params,
    const float* __restrict__ uu,
    float* __restrict__ out)
{
    __shared__ v2f    S[SPAD];         // ~33.3 KB, interleaved (re,im), padded
    __shared__ float4 gco[48];         // per-gate (cc, cs, ss, sc), g = lay*12+q
    __shared__ float  sprob[16];

    const int b = blockIdx.x;
    const int l = threadIdx.x;         // lane 0..63
    const float uval = uu[b];

    // ---- gate coefficients (single wave: no barrier, lgkm-ordered) ----
    if (l < 48) {                      // gate (lay = l/12, q = l%12)
        const int lay = l / 12, q = l - lay * 12;
        float c1, s1, c2, s2;
        sincosf(params[lay * 24 + q] * 0.5f, &s1, &c1);
        sincosf(params[lay * 24 + 12 + q] * 0.5f, &s2, &c2);
        gco[l] = make_float4(c1 * c2, c1 * s2, s1 * s2, s1 * c2); // (cc,cs,ss,sc)
    }

    // ---- CZ sign masks. par(i) = f(lo6) ^ f(hi6) ^ (lo_bit5 & hi_bit0),
    // f(v) = bit v of KPAR. Q block: amp = l*64+j (hi=l, lo=j); P block:
    // amp = j*64+l (hi=j, lo=l). ----
    const unsigned long long parl = ((KPAR >> l) & 1ULL) ? ~0ULL : 0ULL;
    const unsigned long long maskQ =
        KPAR ^ parl ^ ((l & 1)  ? 0xFFFFFFFF00000000ULL : 0ULL);
    const unsigned long long maskP =
        KPAR ^ parl ^ ((l & 32) ? 0xAAAAAAAAAAAAAAAAULL : 0ULL);

    v2f x[64];
    v2f acc2 = (v2f){0.0f, 0.0f};

#pragma unroll 1                       // body ~29 KB: fits L1I, streams 4x
    for (int lay = 0; lay < LAYERS; ++lay) {
        // ---- P pass: qubits 0..5 (amp bits 11:6 in regs) ----
        if (lay == 0) {
            // direct global -> registers in P pattern (coalesced dword loads)
            const float* re = in_re + (size_t)b * DIM + l;
            const float* im = in_im + (size_t)b * DIM + l;
#pragma unroll
            for (int j = 0; j < 64; ++j)
                x[j] = (v2f){re[64 * j], im[64 * j]};
        } else {
#pragma unroll
            for (int j = 0; j < 64; ++j) x[j] = S[65 * j + l];
        }
        apply6(x, gco, lay * 12 + 5);
#pragma unroll
        for (int j = 0; j < 64; ++j) S[65 * j + l] = x[j];

        // ---- Q pass: qubits 6..11 (amp bits 5:0 in regs) + CZ ----
#pragma unroll
        for (int j = 0; j < 64; ++j) x[j] = S[65 * l + j];
        apply6(x, gco, lay * 12 + 11);
        applyCZ64(x, maskQ);           // CZ after all 12 gates of the layer
        if (lay == LAYERS - 1) {
#pragma unroll
            for (int j = 0; j < 64; ++j) acc2 += x[j] * x[j];
        }
#pragma unroll
        for (int j = 0; j < 64; ++j) S[65 * l + j] = x[j];
    }
    (void)maskP;                       // P-partition mask kept for alt schedules

    // ---- ancilla outcome probs: thread's 64 amps (l*64+j) all in outcome l>>2 ----
    {
        float partial = acc2.x + acc2.y;
        partial += __shfl_down(partial, 2, 4);
        partial += __shfl_down(partial, 1, 4);
        if ((l & 3) == 0) sprob[l >> 2] = partial;
    }

    // ---- redundant per-lane inverse-CDF sample (broadcast LDS reads) ----
    {
        float cdf[16];
        float a = 0.0f;
#pragma unroll
        for (int i = 0; i < 16; ++i) { a += sprob[i]; cdf[i] = a; }
        const float thresh = uval * a;
        int m = 0;
#pragma unroll
        for (int i = 15; i >= 0; --i) { if (cdf[i] >= thresh) m = i; }
        const float rn = 1.0f / sqrtf(sprob[m]);

        // ---- collapsed, normalized output: [B, 256, 2]; k = c*64 + l ----
        float2* o2 = (float2*)out + (size_t)b * 256;
#pragma unroll
        for (int c = 0; c < 4; ++c) {
            const v2f amp = S[260 * m + 65 * c + l];   // phys(m*256 + c*64 + l)
            o2[c * 64 + l] = make_float2(amp.x * rn, amp.y * rn);
        }
    }
}

extern "C" void kernel_launch(void* const* d_in, const int* in_sizes, int n_in,
                              void* d_out, int out_size, void* d_ws, size_t ws_size,
                              hipStream_t stream) {
    const float* in_re  = (const float*)d_in[0];
    const float* in_im  = (const float*)d_in[1];
    const float* params = (const float*)d_in[2];
    const float* u      = (const float*)d_in[3];
    float* out = (float*)d_out;
    qddpm_kernel<<<NB, 64, 0, stream>>>(in_re, in_im, params, u, out);
}